// Round 3
// baseline (584.261 us; speedup 1.0000x reference)
//
#include <hip/hip_runtime.h>
#include <math.h>

#define F_IN 165
#define HID 16
#define NPB 64          // nodes per bucket (one wave)
#define NPB_BITS 6
#define MAXBUCK 1792    // 256*7 >= ceil(100000/64)=1563
#define OWN 7
#define CHUNK 6144      // edges per binscatter block

// ---- per-node in-degree (int atomics) ----
__global__ __launch_bounds__(256) void k_count(const int* __restrict__ dst,
                                               int* __restrict__ cnt, int E) {
    int i = blockIdx.x * 256 + threadIdx.x;
    if (i < E) atomicAdd(&cnt[dst[i]], 1);
}

// ---- dinv + bucket histogram (bucket == one 64-lane wave) ----
__global__ __launch_bounds__(256) void k_prep(const int* __restrict__ cnt,
                                              float* __restrict__ dinv,
                                              int* __restrict__ bhist,
                                              int N, int nbuck) {
    int i = blockIdx.x * 256 + threadIdx.x;
    int c = 0;
    if (i < N) { c = cnt[i]; dinv[i] = rsqrtf((float)c + 1.0f); }
    int s = c;
    for (int off = 1; off < 64; off <<= 1) s += __shfl_xor(s, off, 64);
    int wave = i >> 6;
    if ((threadIdx.x & 63) == 0 && wave < nbuck) bhist[wave] = s;
}

// ---- single-block exclusive scan of bucket counts -> bofs, cursor ----
__global__ __launch_bounds__(256) void k_bscan(const int* __restrict__ bhist,
                                               int* __restrict__ bofs,
                                               int* __restrict__ cursor, int nbuck) {
    __shared__ int ps[256];
    int t = threadIdx.x;
    int base = t * OWN;
    int loc[OWN];
    int s = 0;
    for (int k = 0; k < OWN; ++k) {
        int idx = base + k;
        loc[k] = s;
        s += (idx < nbuck) ? bhist[idx] : 0;
    }
    ps[t] = s;
    __syncthreads();
    for (int off = 1; off < 256; off <<= 1) {
        int a = (t >= off) ? ps[t - off] : 0;
        __syncthreads();
        ps[t] += a;
        __syncthreads();
    }
    int excl = ps[t] - s;
    for (int k = 0; k < OWN; ++k) {
        int idx = base + k;
        if (idx < nbuck) {
            int v = excl + loc[k];
            bofs[idx] = v;
            cursor[idx] = v;
        }
    }
    if (t == 255) bofs[nbuck] = ps[255];
}

// ---- counting-sort edges into bucket-major order, packed (src<<6)|dstlow ----
__global__ __launch_bounds__(256) void k_binscatter(const int* __restrict__ src,
                                                    const int* __restrict__ dst,
                                                    int* __restrict__ cursor,
                                                    unsigned* __restrict__ sedge,
                                                    int E, int nbuck) {
    __shared__ int hist[MAXBUCK];    // reused as local cursor in reorder phase
    __shared__ int lofs[MAXBUCK];
    __shared__ int gbase[MAXBUCK];
    __shared__ int ps[256];
    __shared__ unsigned stage[CHUNK];
    int t = threadIdx.x;
    int e0 = blockIdx.x * CHUNK;
    int n = min(CHUNK, E - e0);

    for (int i = t; i < MAXBUCK; i += 256) hist[i] = 0;
    __syncthreads();
    for (int k = t; k < n; k += 256) atomicAdd(&hist[dst[e0 + k] >> NPB_BITS], 1);
    __syncthreads();

    // block exclusive scan of hist -> lofs
    int base = t * OWN;
    int loc[OWN];
    int s = 0;
    for (int k = 0; k < OWN; ++k) { loc[k] = s; s += hist[base + k]; }
    ps[t] = s;
    __syncthreads();
    for (int off = 1; off < 256; off <<= 1) {
        int a = (t >= off) ? ps[t - off] : 0;
        __syncthreads();
        ps[t] += a;
        __syncthreads();
    }
    int excl = ps[t] - s;
    for (int k = 0; k < OWN; ++k) lofs[base + k] = excl + loc[k];
    // reserve global space per non-empty bucket
    for (int i = t; i < nbuck; i += 256) {
        int h = hist[i];
        gbase[i] = h ? atomicAdd(&cursor[i], h) : 0;
    }
    __syncthreads();
    for (int i = t; i < MAXBUCK; i += 256) hist[i] = 0;  // -> local cursor
    __syncthreads();

    // reorder into bucket-major staging
    for (int k = t; k < n; k += 256) {
        int d = dst[e0 + k];
        int sv = src[e0 + k];
        int b = d >> NPB_BITS;
        int r = lofs[b] + atomicAdd(&hist[b], 1);
        stage[r] = ((unsigned)sv << NPB_BITS) | (unsigned)(d & (NPB - 1));
    }
    __syncthreads();

    // coalesced write-out; bucket of slot r via binary search in lofs
    for (int r = t; r < n; r += 256) {
        int lo = 0, hi = nbuck - 1;
        while (lo < hi) {
            int mid = (lo + hi + 1) >> 1;
            if (lofs[mid] <= r) lo = mid; else hi = mid - 1;
        }
        sedge[gbase[lo] + (r - lofs[lo])] = stage[r];
    }
}

// ---- g1 = (x @ W1) * dinv[row]   (LDS-tiled, 64 rows/block) ----
__global__ __launch_bounds__(256) void k_gemm1(const float* __restrict__ x,
                                               const float* __restrict__ W1,
                                               const float* __restrict__ dinv,
                                               float* __restrict__ g1, int N) {
    __shared__ float xs[64 * F_IN];
    int b = blockIdx.x;
    int rows = min(64, N - b * 64);
    int nf = rows * F_IN;
    const float* xbase = x + (long long)b * 64 * F_IN;
    int nf4 = nf >> 2;
    const float4* src4 = (const float4*)xbase;
    float4* xs4 = (float4*)xs;
    for (int i = threadIdx.x; i < nf4; i += 256) xs4[i] = src4[i];
    for (int i = nf4 * 4 + threadIdx.x; i < nf; i += 256) xs[i] = xbase[i];
    __syncthreads();

    int row = threadIdx.x & 63;
    int jq = threadIdx.x >> 6;
    int gi = b * 64 + row;
    if (gi < N && row < rows) {
        float a0 = 0.f, a1 = 0.f, a2 = 0.f, a3 = 0.f;
        for (int k = 0; k < F_IN; ++k) {
            float v = xs[row * F_IN + k];
            const float* w = W1 + k * HID + jq * 4;
            a0 = fmaf(v, w[0], a0);
            a1 = fmaf(v, w[1], a1);
            a2 = fmaf(v, w[2], a2);
            a3 = fmaf(v, w[3], a3);
        }
        float di = dinv[gi];
        float* o = g1 + (long long)gi * HID + jq * 4;
        o[0] = a0 * di; o[1] = a1 * di; o[2] = a2 * di; o[3] = a3 * di;
    }
}

// ---- layer-1 aggregation in LDS + fused bias/relu/W2/rescale -> g2 ----
__global__ __launch_bounds__(256) void k_agg1(const unsigned* __restrict__ sedge,
                                              const int* __restrict__ bofs,
                                              const float* __restrict__ g1,
                                              const float* __restrict__ dinv,
                                              const float* __restrict__ b1,
                                              const float* __restrict__ W2,
                                              float* __restrict__ g2, int N) {
    __shared__ float acc[NPB * 17];
    int t = threadIdx.x;
    int b = blockIdx.x;
    for (int i = t; i < NPB * 17; i += 256) acc[i] = 0.f;
    __syncthreads();
    int e0 = bofs[b], e1 = bofs[b + 1];
    int g = t >> 4;
    int j = t & 15;
    int e = e0 + g;
    for (; e + 48 < e1; e += 64) {
        unsigned p0 = sedge[e], p1 = sedge[e + 16], p2 = sedge[e + 32], p3 = sedge[e + 48];
        float v0 = g1[(p0 >> NPB_BITS) * HID + j];
        float v1 = g1[(p1 >> NPB_BITS) * HID + j];
        float v2 = g1[(p2 >> NPB_BITS) * HID + j];
        float v3 = g1[(p3 >> NPB_BITS) * HID + j];
        atomicAdd(&acc[(p0 & (NPB - 1)) * 17 + j], v0);
        atomicAdd(&acc[(p1 & (NPB - 1)) * 17 + j], v1);
        atomicAdd(&acc[(p2 & (NPB - 1)) * 17 + j], v2);
        atomicAdd(&acc[(p3 & (NPB - 1)) * 17 + j], v3);
    }
    for (; e < e1; e += 16) {
        unsigned p = sedge[e];
        atomicAdd(&acc[(p & (NPB - 1)) * 17 + j], g1[(p >> NPB_BITS) * HID + j]);
    }
    __syncthreads();
    if (t < NPB) {
        int node = b * NPB + t;
        if (node < N) {
            float di = dinv[node];
            float c0 = 0.f, c1 = 0.f;
#pragma unroll
            for (int jj = 0; jj < HID; ++jj) {
                float v = (acc[t * 17 + jj] + g1[node * HID + jj]) * di + b1[jj];
                v = v > 0.f ? v : 0.f;
                c0 = fmaf(v, W2[jj * 2 + 0], c0);
                c1 = fmaf(v, W2[jj * 2 + 1], c1);
            }
            g2[node * 2 + 0] = c0 * di;
            g2[node * 2 + 1] = c1 * di;
        }
    }
}

// ---- layer-2 aggregation in LDS + fused log_softmax -> out ----
__global__ __launch_bounds__(256) void k_agg2(const unsigned* __restrict__ sedge,
                                              const int* __restrict__ bofs,
                                              const float* __restrict__ g2,
                                              const float* __restrict__ dinv,
                                              const float* __restrict__ b2,
                                              float* __restrict__ out, int N) {
    __shared__ float acc[NPB * 3];
    int t = threadIdx.x;
    int b = blockIdx.x;
    for (int i = t; i < NPB * 3; i += 256) acc[i] = 0.f;
    __syncthreads();
    int e0 = bofs[b], e1 = bofs[b + 1];
    int g = t >> 1;
    int j = t & 1;
    int e = e0 + g;
    for (; e + 384 < e1; e += 512) {
        unsigned p0 = sedge[e], p1 = sedge[e + 128], p2 = sedge[e + 256], p3 = sedge[e + 384];
        float v0 = g2[(p0 >> NPB_BITS) * 2 + j];
        float v1 = g2[(p1 >> NPB_BITS) * 2 + j];
        float v2 = g2[(p2 >> NPB_BITS) * 2 + j];
        float v3 = g2[(p3 >> NPB_BITS) * 2 + j];
        atomicAdd(&acc[(p0 & (NPB - 1)) * 3 + j], v0);
        atomicAdd(&acc[(p1 & (NPB - 1)) * 3 + j], v1);
        atomicAdd(&acc[(p2 & (NPB - 1)) * 3 + j], v2);
        atomicAdd(&acc[(p3 & (NPB - 1)) * 3 + j], v3);
    }
    for (; e < e1; e += 128) {
        unsigned p = sedge[e];
        atomicAdd(&acc[(p & (NPB - 1)) * 3 + j], g2[(p >> NPB_BITS) * 2 + j]);
    }
    __syncthreads();
    if (t < NPB) {
        int node = b * NPB + t;
        if (node < N) {
            float di = dinv[node];
            float a = (acc[t * 3 + 0] + g2[node * 2 + 0]) * di + b2[0];
            float c = (acc[t * 3 + 1] + g2[node * 2 + 1]) * di + b2[1];
            float m = fmaxf(a, c);
            float lse = m + logf(expf(a - m) + expf(c - m));
            out[node * 2 + 0] = a - lse;
            out[node * 2 + 1] = c - lse;
        }
    }
}

extern "C" void kernel_launch(void* const* d_in, const int* in_sizes, int n_in,
                              void* d_out, int out_size, void* d_ws, size_t ws_size,
                              hipStream_t stream) {
    const float* x  = (const float*)d_in[0];
    const int*   ei = (const int*)d_in[1];
    const float* W1 = (const float*)d_in[2];
    const float* b1 = (const float*)d_in[3];
    const float* W2 = (const float*)d_in[4];
    const float* b2 = (const float*)d_in[5];
    float* out = (float*)d_out;

    int N = in_sizes[0] / F_IN;
    int E = in_sizes[1] / 2;
    const int* src = ei;
    const int* dst = ei + E;
    int nbuck = (N + NPB - 1) >> NPB_BITS;

    int* cnt      = (int*)d_ws;                 // N
    int* bhist    = cnt + N;                    // nbuck
    int* bofs     = bhist + nbuck;              // nbuck+1
    int* cursor   = bofs + nbuck + 1;           // nbuck
    unsigned* sedge = (unsigned*)(cursor + nbuck);  // E
    float* dinv   = (float*)(sedge + E);        // N
    float* g1     = dinv + N;                   // 16N
    float* g2     = g1 + (long long)16 * N;     // 2N

    hipMemsetAsync(cnt, 0, (size_t)N * sizeof(int), stream);

    k_count<<<(E + 255) / 256, 256, 0, stream>>>(dst, cnt, E);
    k_prep<<<(nbuck * NPB + 255) / 256, 256, 0, stream>>>(cnt, dinv, bhist, N, nbuck);
    k_bscan<<<1, 256, 0, stream>>>(bhist, bofs, cursor, nbuck);
    k_binscatter<<<(E + CHUNK - 1) / CHUNK, 256, 0, stream>>>(src, dst, cursor, sedge, E, nbuck);

    k_gemm1<<<(N + 63) / 64, 256, 0, stream>>>(x, W1, dinv, g1, N);

    k_agg1<<<nbuck, 256, 0, stream>>>(sedge, bofs, g1, dinv, b1, W2, g2, N);
    k_agg2<<<nbuck, 256, 0, stream>>>(sedge, bofs, g2, dinv, b2, out, N);
}

// Round 4
// 321.556 us; speedup vs baseline: 1.8170x; 1.8170x over previous
//
#include <hip/hip_runtime.h>
#include <math.h>

#define F_IN 165
#define HID 16
#define NPB 256         // nodes per bucket
#define NPB_BITS 8
#define MAXB 512        // padded bucket-array size (nbuck=391)
#define CHUNK 6144      // edges per binscatter block
#define SSTAGE 12288    // sortnode LDS staging capacity (avg bucket ~8192)

// ---- per-node in-degree (int atomics) ----
__global__ __launch_bounds__(256) void k_count(const int* __restrict__ dst,
                                               int* __restrict__ cnt, int E) {
    int i = blockIdx.x * 256 + threadIdx.x;
    if (i < E) atomicAdd(&cnt[dst[i]], 1);
}

// ---- dinv + per-bucket (256-node == one block) histogram ----
__global__ __launch_bounds__(256) void k_prep(const int* __restrict__ cnt,
                                              float* __restrict__ dinv,
                                              int* __restrict__ bhist, int N) {
    __shared__ int ws[4];
    int t = threadIdx.x;
    int i = blockIdx.x * 256 + t;
    int c = 0;
    if (i < N) { c = cnt[i]; dinv[i] = rsqrtf((float)c + 1.0f); }
    int s = c;
    for (int off = 1; off < 64; off <<= 1) s += __shfl_xor(s, off, 64);
    if ((t & 63) == 0) ws[t >> 6] = s;
    __syncthreads();
    if (t == 0) bhist[blockIdx.x] = ws[0] + ws[1] + ws[2] + ws[3];
}

// ---- single-block exclusive scan of bucket counts -> bofs, cursor ----
__global__ __launch_bounds__(256) void k_bscan(const int* __restrict__ bhist,
                                               int* __restrict__ bofs,
                                               int* __restrict__ cursor,
                                               int* __restrict__ rowptr,
                                               int nbuck, int N) {
    __shared__ int ps[256];
    int t = threadIdx.x;
    int i0 = 2 * t, i1 = 2 * t + 1;
    int c0 = (i0 < nbuck) ? bhist[i0] : 0;
    int c1 = (i1 < nbuck) ? bhist[i1] : 0;
    int s = c0 + c1;
    ps[t] = s;
    __syncthreads();
    for (int off = 1; off < 256; off <<= 1) {
        int a = (t >= off) ? ps[t - off] : 0;
        __syncthreads();
        ps[t] += a;
        __syncthreads();
    }
    int excl = ps[t] - s;
    if (i0 < nbuck) { bofs[i0] = excl;      cursor[i0] = excl; }
    if (i1 < nbuck) { bofs[i1] = excl + c0; cursor[i1] = excl + c0; }
    if (t == 255) { bofs[nbuck] = ps[255]; rowptr[N] = ps[255]; }
}

// ---- counting-sort edges into bucket-major order, packed (src<<8)|dstlow ----
__global__ __launch_bounds__(256) void k_binscatter(const int* __restrict__ src,
                                                    const int* __restrict__ dst,
                                                    int* __restrict__ cursor,
                                                    unsigned* __restrict__ sedge,
                                                    int E, int nbuck) {
    __shared__ int hist[MAXB];
    __shared__ int lofs[MAXB];
    __shared__ int gbase[MAXB];
    __shared__ int ps[256];
    __shared__ unsigned stage[CHUNK];
    int t = threadIdx.x;
    int e0 = blockIdx.x * CHUNK;
    int n = min(CHUNK, E - e0);

    for (int i = t; i < MAXB; i += 256) hist[i] = 0;
    __syncthreads();
    for (int k = t; k < n; k += 256) atomicAdd(&hist[dst[e0 + k] >> NPB_BITS], 1);
    __syncthreads();

    // block exclusive scan of hist (512 entries, 2 per thread)
    int base = t * 2;
    int h0 = hist[base], h1 = hist[base + 1];
    int s = h0 + h1;
    ps[t] = s;
    __syncthreads();
    for (int off = 1; off < 256; off <<= 1) {
        int a = (t >= off) ? ps[t - off] : 0;
        __syncthreads();
        ps[t] += a;
        __syncthreads();
    }
    int excl = ps[t] - s;
    lofs[base] = excl;
    lofs[base + 1] = excl + h0;
    // reserve global space per non-empty bucket
    for (int i = t; i < nbuck; i += 256) {
        int h = hist[i];
        gbase[i] = h ? atomicAdd(&cursor[i], h) : 0;
    }
    __syncthreads();
    for (int i = t; i < MAXB; i += 256) hist[i] = 0;  // -> local cursor
    __syncthreads();

    // reorder into bucket-major staging
    for (int k = t; k < n; k += 256) {
        int d = dst[e0 + k];
        int sv = src[e0 + k];
        int b = d >> NPB_BITS;
        int r = lofs[b] + atomicAdd(&hist[b], 1);
        stage[r] = ((unsigned)sv << NPB_BITS) | (unsigned)(d & (NPB - 1));
    }
    __syncthreads();

    // coalesced-run write-out; bucket of slot r via binary search in lofs
    for (int r = t; r < n; r += 256) {
        int lo = 0, hi = nbuck - 1;
        while (lo < hi) {
            int mid = (lo + hi + 1) >> 1;
            if (lofs[mid] <= r) lo = mid; else hi = mid - 1;
        }
        sedge[gbase[lo] + (r - lofs[lo])] = stage[r];
    }
}

// ---- within-bucket sort by node -> csr (coalesced), rowptr ----
__global__ __launch_bounds__(256) void k_sortnode(const int* __restrict__ cnt,
                                                  const int* __restrict__ bofs,
                                                  const unsigned* __restrict__ sedge,
                                                  int* __restrict__ csr,
                                                  int* __restrict__ rowptr, int N) {
    __shared__ int lcur[256];
    __shared__ int ps[256];
    __shared__ int stage[SSTAGE];
    int b = blockIdx.x, t = threadIdx.x;
    int node = b * 256 + t;
    int c = (node < N) ? cnt[node] : 0;
    int s = c;
    ps[t] = s;
    __syncthreads();
    for (int off = 1; off < 256; off <<= 1) {
        int a = (t >= off) ? ps[t - off] : 0;
        __syncthreads();
        ps[t] += a;
        __syncthreads();
    }
    int excl = ps[t] - c;
    int base = bofs[b];
    if (node < N) rowptr[node] = base + excl;
    lcur[t] = excl;
    __syncthreads();
    int n = bofs[b + 1] - base;
    bool staged = (n <= SSTAGE);
    for (int k = t; k < n; k += 256) {
        unsigned p = sedge[base + k];
        int d = p & (NPB - 1);
        int pos = atomicAdd(&lcur[d], 1);
        int sv = (int)(p >> NPB_BITS);
        if (staged) stage[pos] = sv;
        else        csr[base + pos] = sv;
    }
    __syncthreads();
    if (staged) {
        for (int k = t; k < n; k += 256) csr[base + k] = stage[k];
    }
}

// ---- g1 = (x @ W1) * dinv[row]   (LDS-tiled, 64 rows/block) ----
__global__ __launch_bounds__(256) void k_gemm1(const float* __restrict__ x,
                                               const float* __restrict__ W1,
                                               const float* __restrict__ dinv,
                                               float* __restrict__ g1, int N) {
    __shared__ float xs[64 * F_IN];
    int b = blockIdx.x;
    int rows = min(64, N - b * 64);
    int nf = rows * F_IN;
    const float* xbase = x + (long long)b * 64 * F_IN;
    int nf4 = nf >> 2;
    const float4* src4 = (const float4*)xbase;
    float4* xs4 = (float4*)xs;
    for (int i = threadIdx.x; i < nf4; i += 256) xs4[i] = src4[i];
    for (int i = nf4 * 4 + threadIdx.x; i < nf; i += 256) xs[i] = xbase[i];
    __syncthreads();

    int row = threadIdx.x & 63;
    int jq = threadIdx.x >> 6;   // wave-uniform -> W1 via scalar loads
    int gi = b * 64 + row;
    if (gi < N && row < rows) {
        float a0 = 0.f, a1 = 0.f, a2 = 0.f, a3 = 0.f;
        for (int k = 0; k < F_IN; ++k) {
            float v = xs[row * F_IN + k];
            const float* w = W1 + k * HID + jq * 4;
            a0 = fmaf(v, w[0], a0);
            a1 = fmaf(v, w[1], a1);
            a2 = fmaf(v, w[2], a2);
            a3 = fmaf(v, w[3], a3);
        }
        float di = dinv[gi];
        float* o = g1 + (long long)gi * HID + jq * 4;
        o[0] = a0 * di; o[1] = a1 * di; o[2] = a2 * di; o[3] = a3 * di;
    }
}

// ---- layer-1 CSR gather, register accumulate, fused bias/relu/W2 -> g2 ----
// 16 lanes per node; 8-wide unrolled MLP
__global__ __launch_bounds__(256) void k_agg1(const int* __restrict__ rowptr,
                                              const int* __restrict__ csr,
                                              const float* __restrict__ g1,
                                              const float* __restrict__ dinv,
                                              const float* __restrict__ b1,
                                              const float* __restrict__ W2,
                                              float* __restrict__ g2, int N) {
    int gid = blockIdx.x * 256 + threadIdx.x;
    int i = gid >> 4;
    int j = gid & 15;
    if (i >= N) return;
    int e0 = rowptr[i], e1 = rowptr[i + 1];
    float acc = g1[i * HID + j];  // self-loop term
    int e = e0;
    for (; e + 8 <= e1; e += 8) {
        int s0 = csr[e],     s1 = csr[e + 1], s2 = csr[e + 2], s3 = csr[e + 3];
        int s4 = csr[e + 4], s5 = csr[e + 5], s6 = csr[e + 6], s7 = csr[e + 7];
        float v0 = g1[s0 * HID + j], v1 = g1[s1 * HID + j];
        float v2 = g1[s2 * HID + j], v3 = g1[s3 * HID + j];
        float v4 = g1[s4 * HID + j], v5 = g1[s5 * HID + j];
        float v6 = g1[s6 * HID + j], v7 = g1[s7 * HID + j];
        acc += ((v0 + v1) + (v2 + v3)) + ((v4 + v5) + (v6 + v7));
    }
    for (; e < e1; ++e) acc += g1[csr[e] * HID + j];
    float di = dinv[i];
    float v = fmaf(acc, di, b1[j]);
    v = v > 0.f ? v : 0.f;
    float2 w = ((const float2*)W2)[j];
    float c0 = v * w.x;
    float c1 = v * w.y;
    for (int off = 8; off; off >>= 1) {
        c0 += __shfl_xor(c0, off, 16);
        c1 += __shfl_xor(c1, off, 16);
    }
    if (j == 0) ((float2*)g2)[i] = make_float2(c0 * di, c1 * di);
}

// ---- layer-2 CSR gather + fused log_softmax -> out (4 lanes/node) ----
__global__ __launch_bounds__(256) void k_agg2(const int* __restrict__ rowptr,
                                              const int* __restrict__ csr,
                                              const float* __restrict__ g2,
                                              const float* __restrict__ dinv,
                                              const float* __restrict__ b2,
                                              float* __restrict__ out, int N) {
    int gid = blockIdx.x * 256 + threadIdx.x;
    int i = gid >> 2;
    int l = gid & 3;
    if (i >= N) return;
    int e0 = rowptr[i], e1 = rowptr[i + 1];
    float a0 = 0.f, a1 = 0.f;
    int e = e0 + l;
    for (; e + 4 < e1; e += 8) {
        int s0 = csr[e], s1 = csr[e + 4];
        float2 u = ((const float2*)g2)[s0];
        float2 w = ((const float2*)g2)[s1];
        a0 += u.x + w.x;
        a1 += u.y + w.y;
    }
    for (; e < e1; e += 4) {
        int s = csr[e];
        float2 u = ((const float2*)g2)[s];
        a0 += u.x;
        a1 += u.y;
    }
    a0 += __shfl_xor(a0, 1, 4); a0 += __shfl_xor(a0, 2, 4);
    a1 += __shfl_xor(a1, 1, 4); a1 += __shfl_xor(a1, 2, 4);
    if (l == 0) {
        float2 self = ((const float2*)g2)[i];
        float di = dinv[i];
        float A = fmaf(a0 + self.x, di, b2[0]);
        float B = fmaf(a1 + self.y, di, b2[1]);
        float m = fmaxf(A, B);
        float lse = m + logf(expf(A - m) + expf(B - m));
        ((float2*)out)[i] = make_float2(A - lse, B - lse);
    }
}

extern "C" void kernel_launch(void* const* d_in, const int* in_sizes, int n_in,
                              void* d_out, int out_size, void* d_ws, size_t ws_size,
                              hipStream_t stream) {
    const float* x  = (const float*)d_in[0];
    const int*   ei = (const int*)d_in[1];
    const float* W1 = (const float*)d_in[2];
    const float* b1 = (const float*)d_in[3];
    const float* W2 = (const float*)d_in[4];
    const float* b2 = (const float*)d_in[5];
    float* out = (float*)d_out;

    int N = in_sizes[0] / F_IN;
    int E = in_sizes[1] / 2;
    const int* src = ei;
    const int* dst = ei + E;
    int nbuck = (N + NPB - 1) >> NPB_BITS;

    int* cnt      = (int*)d_ws;                     // N
    int* bhist    = cnt + N;                        // MAXB
    int* bofs     = bhist + MAXB;                   // MAXB+1
    int* cursor   = bofs + MAXB + 1;                // MAXB
    int* rowptr   = cursor + MAXB;                  // N+1
    unsigned* sedge = (unsigned*)(rowptr + N + 1);  // E
    int* csr      = (int*)(sedge + E);              // E
    float* dinv   = (float*)(csr + E);              // N
    float* g1     = dinv + N;                       // 16N
    float* g2     = g1 + (long long)16 * N;         // 2N

    hipMemsetAsync(cnt, 0, (size_t)N * sizeof(int), stream);

    k_count<<<(E + 255) / 256, 256, 0, stream>>>(dst, cnt, E);
    k_prep<<<nbuck, 256, 0, stream>>>(cnt, dinv, bhist, N);
    k_bscan<<<1, 256, 0, stream>>>(bhist, bofs, cursor, rowptr, nbuck, N);
    k_binscatter<<<(E + CHUNK - 1) / CHUNK, 256, 0, stream>>>(src, dst, cursor, sedge, E, nbuck);
    k_sortnode<<<nbuck, 256, 0, stream>>>(cnt, bofs, sedge, csr, rowptr, N);

    k_gemm1<<<(N + 63) / 64, 256, 0, stream>>>(x, W1, dinv, g1, N);

    k_agg1<<<(N * 16 + 255) / 256, 256, 0, stream>>>(rowptr, csr, g1, dinv, b1, W2, g2, N);
    k_agg2<<<(N * 4 + 255) / 256, 256, 0, stream>>>(rowptr, csr, g2, dinv, b2, out, N);
}

// Round 5
// 211.251 us; speedup vs baseline: 2.7657x; 1.5221x over previous
//
#include <hip/hip_runtime.h>
#include <math.h>

#define F_IN 165
#define HID 16
#define NPB 256         // nodes per bucket
#define NPB_BITS 8
#define MAXB 512        // padded bucket-array size (nbuck=391)
#define CHUNK 6144      // edges per binscatter block
#define SSTAGE 12288    // sortnode LDS staging capacity (avg bucket ~8192)
#define HB_BLOCKS 256   // k_bhist grid

// ---- bucket histogram: LDS-staged, ~100k global atomics total ----
__global__ __launch_bounds__(256) void k_bhist(const int* __restrict__ dst,
                                               int* __restrict__ bhist,
                                               int E, int nbuck) {
    __shared__ int h[MAXB];
    int t = threadIdx.x;
    for (int i = t; i < MAXB; i += 256) h[i] = 0;
    __syncthreads();
    int per = (E + gridDim.x - 1) / gridDim.x;
    int s0 = blockIdx.x * per;
    int s1 = min(E, s0 + per);
    for (int k = s0 + t; k < s1; k += 256)
        atomicAdd(&h[dst[k] >> NPB_BITS], 1);
    __syncthreads();
    for (int i = t; i < nbuck; i += 256) {
        int v = h[i];
        if (v) atomicAdd(&bhist[i], v);
    }
}

// ---- single-block exclusive scan of bucket counts -> bofs, cursor ----
__global__ __launch_bounds__(256) void k_bscan(const int* __restrict__ bhist,
                                               int* __restrict__ bofs,
                                               int* __restrict__ cursor,
                                               int* __restrict__ rowptr,
                                               int nbuck, int N) {
    __shared__ int ps[256];
    int t = threadIdx.x;
    int i0 = 2 * t, i1 = 2 * t + 1;
    int c0 = (i0 < nbuck) ? bhist[i0] : 0;
    int c1 = (i1 < nbuck) ? bhist[i1] : 0;
    int s = c0 + c1;
    ps[t] = s;
    __syncthreads();
    for (int off = 1; off < 256; off <<= 1) {
        int a = (t >= off) ? ps[t - off] : 0;
        __syncthreads();
        ps[t] += a;
        __syncthreads();
    }
    int excl = ps[t] - s;
    if (i0 < nbuck) { bofs[i0] = excl;      cursor[i0] = excl; }
    if (i1 < nbuck) { bofs[i1] = excl + c0; cursor[i1] = excl + c0; }
    if (t == 255) { bofs[nbuck] = ps[255]; rowptr[N] = ps[255]; }
}

// ---- counting-sort edges into bucket-major order, packed (src<<8)|dstlow ----
__global__ __launch_bounds__(256) void k_binscatter(const int* __restrict__ src,
                                                    const int* __restrict__ dst,
                                                    int* __restrict__ cursor,
                                                    unsigned* __restrict__ sedge,
                                                    int E, int nbuck) {
    __shared__ int hist[MAXB];
    __shared__ int lofs[MAXB];
    __shared__ int gbase[MAXB];
    __shared__ int ps[256];
    __shared__ unsigned stage[CHUNK];
    int t = threadIdx.x;
    int e0 = blockIdx.x * CHUNK;
    int n = min(CHUNK, E - e0);

    for (int i = t; i < MAXB; i += 256) hist[i] = 0;
    __syncthreads();
    for (int k = t; k < n; k += 256) atomicAdd(&hist[dst[e0 + k] >> NPB_BITS], 1);
    __syncthreads();

    // block exclusive scan of hist (512 entries, 2 per thread)
    int base = t * 2;
    int h0 = hist[base], h1 = hist[base + 1];
    int s = h0 + h1;
    ps[t] = s;
    __syncthreads();
    for (int off = 1; off < 256; off <<= 1) {
        int a = (t >= off) ? ps[t - off] : 0;
        __syncthreads();
        ps[t] += a;
        __syncthreads();
    }
    int excl = ps[t] - s;
    lofs[base] = excl;
    lofs[base + 1] = excl + h0;
    // reserve global space per non-empty bucket
    for (int i = t; i < nbuck; i += 256) {
        int h = hist[i];
        gbase[i] = h ? atomicAdd(&cursor[i], h) : 0;
    }
    __syncthreads();
    for (int i = t; i < MAXB; i += 256) hist[i] = 0;  // -> local cursor
    __syncthreads();

    // reorder into bucket-major staging
    for (int k = t; k < n; k += 256) {
        int d = dst[e0 + k];
        int sv = src[e0 + k];
        int b = d >> NPB_BITS;
        int r = lofs[b] + atomicAdd(&hist[b], 1);
        stage[r] = ((unsigned)sv << NPB_BITS) | (unsigned)(d & (NPB - 1));
    }
    __syncthreads();

    // coalesced-run write-out; bucket of slot r via binary search in lofs
    for (int r = t; r < n; r += 256) {
        int lo = 0, hi = nbuck - 1;
        while (lo < hi) {
            int mid = (lo + hi + 1) >> 1;
            if (lofs[mid] <= r) lo = mid; else hi = mid - 1;
        }
        sedge[gbase[lo] + (r - lofs[lo])] = stage[r];
    }
}

// ---- within-bucket: node histogram (LDS) -> rowptr + dinv + sorted csr ----
__global__ __launch_bounds__(256) void k_sortnode(const int* __restrict__ bofs,
                                                  const unsigned* __restrict__ sedge,
                                                  int* __restrict__ csr,
                                                  int* __restrict__ rowptr,
                                                  float* __restrict__ dinv, int N) {
    __shared__ int hist[256];
    __shared__ int ps[256];
    __shared__ int lcur[256];
    __shared__ int stage[SSTAGE];
    int b = blockIdx.x, t = threadIdx.x;
    int base = bofs[b];
    int n = bofs[b + 1] - base;
    hist[t] = 0;
    __syncthreads();
    for (int k = t; k < n; k += 256)
        atomicAdd(&hist[sedge[base + k] & (NPB - 1)], 1);
    __syncthreads();
    int c = hist[t];
    ps[t] = c;
    __syncthreads();
    for (int off = 1; off < 256; off <<= 1) {
        int a = (t >= off) ? ps[t - off] : 0;
        __syncthreads();
        ps[t] += a;
        __syncthreads();
    }
    int excl = ps[t] - c;
    int node = b * NPB + t;
    if (node < N) {
        rowptr[node] = base + excl;
        dinv[node] = rsqrtf((float)c + 1.0f);
    }
    lcur[t] = excl;
    __syncthreads();
    bool staged = (n <= SSTAGE);
    for (int k = t; k < n; k += 256) {
        unsigned p = sedge[base + k];
        int d = p & (NPB - 1);
        int pos = atomicAdd(&lcur[d], 1);
        int sv = (int)(p >> NPB_BITS);
        if (staged) stage[pos] = sv;
        else        csr[base + pos] = sv;
    }
    __syncthreads();
    if (staged) {
        for (int k = t; k < n; k += 256) csr[base + k] = stage[k];
    }
}

// ---- g1 = (x @ W1) * dinv[row]   (LDS-tiled, 64 rows/block) ----
__global__ __launch_bounds__(256) void k_gemm1(const float* __restrict__ x,
                                               const float* __restrict__ W1,
                                               const float* __restrict__ dinv,
                                               float* __restrict__ g1, int N) {
    __shared__ float xs[64 * F_IN];
    int b = blockIdx.x;
    int rows = min(64, N - b * 64);
    int nf = rows * F_IN;
    const float* xbase = x + (long long)b * 64 * F_IN;
    int nf4 = nf >> 2;
    const float4* src4 = (const float4*)xbase;
    float4* xs4 = (float4*)xs;
    for (int i = threadIdx.x; i < nf4; i += 256) xs4[i] = src4[i];
    for (int i = nf4 * 4 + threadIdx.x; i < nf; i += 256) xs[i] = xbase[i];
    __syncthreads();

    int row = threadIdx.x & 63;
    int jq = threadIdx.x >> 6;   // wave-uniform -> W1 via scalar loads
    int gi = b * 64 + row;
    if (gi < N && row < rows) {
        float a0 = 0.f, a1 = 0.f, a2 = 0.f, a3 = 0.f;
        for (int k = 0; k < F_IN; ++k) {
            float v = xs[row * F_IN + k];
            const float* w = W1 + k * HID + jq * 4;
            a0 = fmaf(v, w[0], a0);
            a1 = fmaf(v, w[1], a1);
            a2 = fmaf(v, w[2], a2);
            a3 = fmaf(v, w[3], a3);
        }
        float di = dinv[gi];
        float* o = g1 + (long long)gi * HID + jq * 4;
        o[0] = a0 * di; o[1] = a1 * di; o[2] = a2 * di; o[3] = a3 * di;
    }
}

// ---- layer-1 CSR gather, register accumulate, fused bias/relu/W2 -> g2 ----
__global__ __launch_bounds__(256) void k_agg1(const int* __restrict__ rowptr,
                                              const int* __restrict__ csr,
                                              const float* __restrict__ g1,
                                              const float* __restrict__ dinv,
                                              const float* __restrict__ b1,
                                              const float* __restrict__ W2,
                                              float* __restrict__ g2, int N) {
    int gid = blockIdx.x * 256 + threadIdx.x;
    int i = gid >> 4;
    int j = gid & 15;
    if (i >= N) return;
    int e0 = rowptr[i], e1 = rowptr[i + 1];
    float acc = g1[i * HID + j];  // self-loop term
    int e = e0;
    for (; e + 8 <= e1; e += 8) {
        int s0 = csr[e],     s1 = csr[e + 1], s2 = csr[e + 2], s3 = csr[e + 3];
        int s4 = csr[e + 4], s5 = csr[e + 5], s6 = csr[e + 6], s7 = csr[e + 7];
        float v0 = g1[s0 * HID + j], v1 = g1[s1 * HID + j];
        float v2 = g1[s2 * HID + j], v3 = g1[s3 * HID + j];
        float v4 = g1[s4 * HID + j], v5 = g1[s5 * HID + j];
        float v6 = g1[s6 * HID + j], v7 = g1[s7 * HID + j];
        acc += ((v0 + v1) + (v2 + v3)) + ((v4 + v5) + (v6 + v7));
    }
    for (; e < e1; ++e) acc += g1[csr[e] * HID + j];
    float di = dinv[i];
    float v = fmaf(acc, di, b1[j]);
    v = v > 0.f ? v : 0.f;
    float2 w = ((const float2*)W2)[j];
    float c0 = v * w.x;
    float c1 = v * w.y;
    for (int off = 8; off; off >>= 1) {
        c0 += __shfl_xor(c0, off, 16);
        c1 += __shfl_xor(c1, off, 16);
    }
    if (j == 0) ((float2*)g2)[i] = make_float2(c0 * di, c1 * di);
}

// ---- layer-2 CSR gather + fused log_softmax -> out (4 lanes/node) ----
__global__ __launch_bounds__(256) void k_agg2(const int* __restrict__ rowptr,
                                              const int* __restrict__ csr,
                                              const float* __restrict__ g2,
                                              const float* __restrict__ dinv,
                                              const float* __restrict__ b2,
                                              float* __restrict__ out, int N) {
    int gid = blockIdx.x * 256 + threadIdx.x;
    int i = gid >> 2;
    int l = gid & 3;
    if (i >= N) return;
    int e0 = rowptr[i], e1 = rowptr[i + 1];
    float a0 = 0.f, a1 = 0.f;
    int e = e0 + l;
    for (; e + 4 < e1; e += 8) {
        int s0 = csr[e], s1 = csr[e + 4];
        float2 u = ((const float2*)g2)[s0];
        float2 w = ((const float2*)g2)[s1];
        a0 += u.x + w.x;
        a1 += u.y + w.y;
    }
    for (; e < e1; e += 4) {
        int s = csr[e];
        float2 u = ((const float2*)g2)[s];
        a0 += u.x;
        a1 += u.y;
    }
    a0 += __shfl_xor(a0, 1, 4); a0 += __shfl_xor(a0, 2, 4);
    a1 += __shfl_xor(a1, 1, 4); a1 += __shfl_xor(a1, 2, 4);
    if (l == 0) {
        float2 self = ((const float2*)g2)[i];
        float di = dinv[i];
        float A = fmaf(a0 + self.x, di, b2[0]);
        float B = fmaf(a1 + self.y, di, b2[1]);
        float m = fmaxf(A, B);
        float lse = m + logf(expf(A - m) + expf(B - m));
        ((float2*)out)[i] = make_float2(A - lse, B - lse);
    }
}

extern "C" void kernel_launch(void* const* d_in, const int* in_sizes, int n_in,
                              void* d_out, int out_size, void* d_ws, size_t ws_size,
                              hipStream_t stream) {
    const float* x  = (const float*)d_in[0];
    const int*   ei = (const int*)d_in[1];
    const float* W1 = (const float*)d_in[2];
    const float* b1 = (const float*)d_in[3];
    const float* W2 = (const float*)d_in[4];
    const float* b2 = (const float*)d_in[5];
    float* out = (float*)d_out;

    int N = in_sizes[0] / F_IN;
    int E = in_sizes[1] / 2;
    const int* src = ei;
    const int* dst = ei + E;
    int nbuck = (N + NPB - 1) >> NPB_BITS;

    int* bhist    = (int*)d_ws;                     // MAXB
    int* bofs     = bhist + MAXB;                   // MAXB+1
    int* cursor   = bofs + MAXB + 1;                // MAXB
    int* rowptr   = cursor + MAXB;                  // N+1
    unsigned* sedge = (unsigned*)(rowptr + N + 1);  // E
    int* csr      = (int*)(sedge + E);              // E
    float* dinv   = (float*)(csr + E);              // N
    float* g1     = dinv + N;                       // 16N
    float* g2     = g1 + (long long)16 * N;         // 2N

    hipMemsetAsync(bhist, 0, (size_t)MAXB * sizeof(int), stream);

    k_bhist<<<HB_BLOCKS, 256, 0, stream>>>(dst, bhist, E, nbuck);
    k_bscan<<<1, 256, 0, stream>>>(bhist, bofs, cursor, rowptr, nbuck, N);
    k_binscatter<<<(E + CHUNK - 1) / CHUNK, 256, 0, stream>>>(src, dst, cursor, sedge, E, nbuck);
    k_sortnode<<<nbuck, 256, 0, stream>>>(bofs, sedge, csr, rowptr, dinv, N);

    k_gemm1<<<(N + 63) / 64, 256, 0, stream>>>(x, W1, dinv, g1, N);

    k_agg1<<<(N * 16 + 255) / 256, 256, 0, stream>>>(rowptr, csr, g1, dinv, b1, W2, g2, N);
    k_agg2<<<(N * 4 + 255) / 256, 256, 0, stream>>>(rowptr, csr, g2, dinv, b2, out, N);
}